// Round 1
// baseline (340.804 us; speedup 1.0000x reference)
//
#include <hip/hip_runtime.h>
#include <math.h>

// Problem constants
#define DM 1024      // d_model
#define LL 2048      // sequence length
#define BB 4         // batch
#define HH 16        // heads
#define HD 64        // head dim
#define CC 64        // chunk size
#define NC (LL / CC) // 32 chunks
#define EPSC 1e-6f
#define PS 72        // padded LDS stride (elements) for VALU-written 64-wide tiles

typedef __attribute__((ext_vector_type(8))) short short8;      // 8 bf16
typedef __attribute__((ext_vector_type(8))) _Float16 half8;    // 8 f16
typedef __attribute__((ext_vector_type(4))) float floatx4;     // MFMA acc

__device__ __forceinline__ float featf(float x) { return x > 0.f ? x + 1.f : __expf(x); }

// round-to-nearest-even f32 -> bf16 bits
__device__ __forceinline__ unsigned short f2bf(float f) {
    unsigned int u = __builtin_bit_cast(unsigned int, f);
    u = (u + 0x7FFFu + ((u >> 16) & 1u)) >> 16;
    return (unsigned short)u;
}

// 8x f32 -> 8x bf16 via hardware pk converts (RNE, matches f2bf)
__device__ __forceinline__ short8 cvt8(float4 a, float4 b) {
    union { unsigned int u[4]; short8 v; } r;
    asm("v_cvt_pk_bf16_f32 %0, %1, %2" : "=v"(r.u[0]) : "v"(a.x), "v"(a.y));
    asm("v_cvt_pk_bf16_f32 %0, %1, %2" : "=v"(r.u[1]) : "v"(a.z), "v"(a.w));
    asm("v_cvt_pk_bf16_f32 %0, %1, %2" : "=v"(r.u[2]) : "v"(b.x), "v"(b.y));
    asm("v_cvt_pk_bf16_f32 %0, %1, %2" : "=v"(r.u[3]) : "v"(b.z), "v"(b.w));
    return r.v;
}

__device__ __forceinline__ void gload_lds16(const void* g, void* l) {
    __builtin_amdgcn_global_load_lds(
        (const __attribute__((address_space(1))) void*)g,
        (__attribute__((address_space(3))) void*)l,
        16, 0, 0);
}

// Stage a 64x64 2-byte-element tile (8 KB) global -> LDS, XOR-8 chunk swizzle
// baked into the SOURCE address. LDS: row*128B + slot*16B, slot = g ^ (row&7).
__device__ __forceinline__ void stage_tile(const void* gp_, int rowstride,
                                           char* lds_base, int tid) {
    const unsigned short* gp = (const unsigned short*)gp_;
#pragma unroll
    for (int m = 0; m < 2; ++m) {
        const int row = m * 32 + (tid >> 3);
        const int g = (tid & 7) ^ (row & 7);
        gload_lds16(gp + (size_t)row * rowstride + g * 8,
                    lds_base + m * 4096 + tid * 16);
    }
}
__device__ __forceinline__ half8 frag_ldh(const char* base, int row, int kc) {
    return *(const half8*)(base + row * 128 + (((kc) ^ (row & 7)) << 4));
}

// ---------------------------------------------------------------------------
// fused weight transpose+convert: W [K][N] f32 -> Wt [N][K] bf16, 4 weights
// ---------------------------------------------------------------------------
__global__ __launch_bounds__(256) void transpose4(
    const float* __restrict__ W0, const float* __restrict__ W1,
    const float* __restrict__ W2, const float* __restrict__ W3,
    unsigned short* __restrict__ T0, unsigned short* __restrict__ T1,
    unsigned short* __restrict__ T2, unsigned short* __restrict__ T3)
{
    __shared__ float tile[64][65];
    const int sel = blockIdx.z;
    const float* W = (sel == 0) ? W0 : (sel == 1) ? W1 : (sel == 2) ? W2 : W3;
    unsigned short* Wt = (sel == 0) ? T0 : (sel == 1) ? T1 : (sel == 2) ? T2 : T3;
    const int r0 = blockIdx.y * 64, c0 = blockIdx.x * 64;
    const int tid = threadIdx.x;
#pragma unroll
    for (int e = 0; e < 16; ++e) {
        const int idx = e * 256 + tid;
        const int r = idx >> 6, c = idx & 63;
        tile[r][c] = W[(size_t)(r0 + r) * DM + c0 + c];
    }
    __syncthreads();
#pragma unroll
    for (int e = 0; e < 16; ++e) {
        const int idx = e * 256 + tid;
        const int co = idx >> 6, ro = idx & 63;
        Wt[(size_t)(c0 + co) * DM + r0 + ro] = f2bf(tile[ro][co]);
    }
}

// ===========================================================================
// gemm_qkv: fused f32->bf16 convert + MFMA GEMM for the three projections.
// A-side: reads f32 inputs directly, cvt_pk in regs, ds_write into the
// XOR-swizzled tile (next k-step's loads issued under the MFMA block).
// B-side: bf16 Wt via global_load_lds (unchanged).
// sel 0: Q (act, row-major f16) sel 1: K (act, KT-chunk) sel 2: V (row-major)
// Grid (512, 3); XCD-chunked swizzle so the 8 n-blocks of one m-strip share
// one XCD's L2 (A strip re-read 8x stays local).
// ===========================================================================
__global__ __launch_bounds__(256) void gemm_qkv(
    const float* __restrict__ Xq, const float* __restrict__ Xk,
    const float* __restrict__ Xv,
    const unsigned short* __restrict__ Wqt, const unsigned short* __restrict__ Wkt,
    const unsigned short* __restrict__ Wvt,
    const float* __restrict__ bq, const float* __restrict__ bk,
    const float* __restrict__ bv,
    _Float16* __restrict__ Qh, _Float16* __restrict__ KTp,
    _Float16* __restrict__ Vh)
{
    __shared__ __align__(16) unsigned short As[128 * 32];
    __shared__ __align__(16) unsigned short Bs[128 * 32];

    const int sel = blockIdx.y;
    const float* Xf = (sel == 0) ? Xq : (sel == 1) ? Xk : Xv;
    const unsigned short* Wt = (sel == 0) ? Wqt : (sel == 1) ? Wkt : Wvt;
    const float* bias = (sel == 0) ? bq : (sel == 1) ? bk : bv;

    const int tid = threadIdx.x;
    const int lane = tid & 63;
    const int w = tid >> 6;
    const int wr = w >> 1, wc = w & 1;
    const int fm = lane & 15;
    const int fq = lane >> 4;
    // bijective XCD-chunk swizzle: XCD x gets 8 complete m-strips (all n)
    const int t = (blockIdx.x & 7) * 64 + (blockIdx.x >> 3);
    const int n0 = (t & 7) * 128, m0 = (t >> 3) * 128;

    floatx4 acc[4][4];
#pragma unroll
    for (int i = 0; i < 4; ++i)
#pragma unroll
        for (int j = 0; j < 4; ++j) acc[i][j] = (floatx4){0.f, 0.f, 0.f, 0.f};

    const int row0 = tid >> 2;
    const int row1 = row0 + 64;
    const int slot0 = (tid & 3) ^ (row0 & 3);
    const int slot1 = (tid & 3) ^ (row1 & 3);
    const float* Xa = Xf + (size_t)(m0 + row0) * DM + slot0 * 8;
    const float* Xb = Xf + (size_t)(m0 + row1) * DM + slot1 * 8;
    const unsigned short* Wa = Wt + (size_t)(n0 + row0) * DM + slot0 * 8;
    const unsigned short* Wb = Wt + (size_t)(n0 + row1) * DM + slot1 * 8;

    const int fswz = ((fq ^ (fm & 3)) << 3);

    // prologue: k0 = 0 A-tile loads
    float4 ra0 = *(const float4*)(Xa);
    float4 ra1 = *(const float4*)(Xa + 4);
    float4 rb0 = *(const float4*)(Xb);
    float4 rb1 = *(const float4*)(Xb + 4);

    for (int k0 = 0; k0 < DM; k0 += 32) {
        gload_lds16(Wa + k0, Bs + (size_t)tid * 8);
        gload_lds16(Wb + k0, Bs + (size_t)(256 + tid) * 8);
        *(short8*)(As + (size_t)tid * 8) = cvt8(ra0, ra1);
        *(short8*)(As + (size_t)(256 + tid) * 8) = cvt8(rb0, rb1);
        __syncthreads();

        // issue next k-step's f32 loads; they fly under the MFMA block
        const int kn = (k0 + 32 < DM) ? (k0 + 32) : 0;
        ra0 = *(const float4*)(Xa + kn);
        ra1 = *(const float4*)(Xa + kn + 4);
        rb0 = *(const float4*)(Xb + kn);
        rb1 = *(const float4*)(Xb + kn + 4);

        short8 af[4], bf[4];
#pragma unroll
        for (int mt = 0; mt < 4; ++mt)
            af[mt] = *(const short8*)(As + (wr * 64 + mt * 16 + fm) * 32 + fswz);
#pragma unroll
        for (int nt = 0; nt < 4; ++nt)
            bf[nt] = *(const short8*)(Bs + (wc * 64 + nt * 16 + fm) * 32 + fswz);
#pragma unroll
        for (int mt = 0; mt < 4; ++mt)
#pragma unroll
            for (int nt = 0; nt < 4; ++nt)
                acc[mt][nt] = __builtin_amdgcn_mfma_f32_16x16x32_bf16(
                    af[mt], bf[nt], acc[mt][nt], 0, 0, 0);
        __syncthreads();
    }

    if (sel != 1) {
        // row-major f16 plane out (Q with act, V without)
        const int act = (sel == 0);
        _Float16* Yh = (sel == 0) ? Qh : Vh;
#pragma unroll
        for (int nt = 0; nt < 4; ++nt) {
            const int col = n0 + wc * 64 + nt * 16 + fm;
            const float bvv = bias[col];
#pragma unroll
            for (int mt = 0; mt < 4; ++mt) {
                const int rbase = m0 + wr * 64 + mt * 16 + fq * 4;
#pragma unroll
                for (int r = 0; r < 4; ++r) {
                    float v = acc[mt][nt][r] + bvv;
                    if (act) v = featf(v);
                    Yh[(size_t)(rbase + r) * DM + col] = (_Float16)v;
                }
            }
        }
    } else {
        // KT-chunk layout [blk][j][t], blk = (b*16+h)*32 + chunk; act always
        const int b = m0 >> 11;
        const int cch = ((m0 & 2047) >> 6) + wr;
        const int h = (n0 >> 6) + wc;
        _Float16* hb = KTp + ((size_t)((b * 16 + h) * 32 + cch)) * 4096;
#pragma unroll
        for (int nt = 0; nt < 4; ++nt) {
            const int j = nt * 16 + fm;
            const float bvv = bias[n0 + wc * 64 + nt * 16 + fm];
#pragma unroll
            for (int mt = 0; mt < 4; ++mt) {
                float o[4];
#pragma unroll
                for (int r = 0; r < 4; ++r)
                    o[r] = featf(acc[mt][nt][r] + bvv);
                union { _Float16 h[4]; uint2 v; } pk;
#pragma unroll
                for (int r = 0; r < 4; ++r) pk.h[r] = (_Float16)o[r];
                *(uint2*)(hb + j * 64 + mt * 16 + fq * 4) = pk.v;
            }
        }
    }
}

// ---------------------------------------------------------------------------
// gemm_out: bf16 MFMA GEMM, f32 rows out (final output projection)
// ---------------------------------------------------------------------------
__global__ __launch_bounds__(256) void gemm_out(
    const unsigned short* __restrict__ X,
    const unsigned short* __restrict__ Wt,
    const float* __restrict__ bias,
    float* __restrict__ Yf)
{
    __shared__ __align__(16) unsigned short As[128 * 32];
    __shared__ __align__(16) unsigned short Bs[128 * 32];

    const int tid = threadIdx.x;
    const int lane = tid & 63;
    const int w = tid >> 6;
    const int wr = w >> 1, wc = w & 1;
    const int fm = lane & 15;
    const int fq = lane >> 4;
    const int t = (blockIdx.x & 7) * 64 + (blockIdx.x >> 3);
    const int n0 = (t & 7) * 128, m0 = (t >> 3) * 128;

    floatx4 acc[4][4];
#pragma unroll
    for (int i = 0; i < 4; ++i)
#pragma unroll
        for (int j = 0; j < 4; ++j) acc[i][j] = (floatx4){0.f, 0.f, 0.f, 0.f};

    const int row0 = tid >> 2;
    const int row1 = row0 + 64;
    const int slot0 = (tid & 3) ^ (row0 & 3);
    const int slot1 = (tid & 3) ^ (row1 & 3);
    const unsigned short* Xa = X + (size_t)(m0 + row0) * DM + slot0 * 8;
    const unsigned short* Xb = X + (size_t)(m0 + row1) * DM + slot1 * 8;
    const unsigned short* Wa = Wt + (size_t)(n0 + row0) * DM + slot0 * 8;
    const unsigned short* Wb = Wt + (size_t)(n0 + row1) * DM + slot1 * 8;

    const int fswz = ((fq ^ (fm & 3)) << 3);

    for (int k0 = 0; k0 < DM; k0 += 32) {
        gload_lds16(Xa + k0, As + (size_t)tid * 8);
        gload_lds16(Xb + k0, As + (size_t)(256 + tid) * 8);
        gload_lds16(Wa + k0, Bs + (size_t)tid * 8);
        gload_lds16(Wb + k0, Bs + (size_t)(256 + tid) * 8);
        __syncthreads();

        short8 af[4], bf[4];
#pragma unroll
        for (int mt = 0; mt < 4; ++mt)
            af[mt] = *(const short8*)(As + (wr * 64 + mt * 16 + fm) * 32 + fswz);
#pragma unroll
        for (int nt = 0; nt < 4; ++nt)
            bf[nt] = *(const short8*)(Bs + (wc * 64 + nt * 16 + fm) * 32 + fswz);
#pragma unroll
        for (int mt = 0; mt < 4; ++mt)
#pragma unroll
            for (int nt = 0; nt < 4; ++nt)
                acc[mt][nt] = __builtin_amdgcn_mfma_f32_16x16x32_bf16(
                    af[mt], bf[nt], acc[mt][nt], 0, 0, 0);
        __syncthreads();
    }

#pragma unroll
    for (int nt = 0; nt < 4; ++nt) {
        const int col = n0 + wc * 64 + nt * 16 + fm;
        const float bv = bias[col];
#pragma unroll
        for (int mt = 0; mt < 4; ++mt) {
            const int rbase = m0 + wr * 64 + mt * 16 + fq * 4;
#pragma unroll
            for (int r = 0; r < 4; ++r)
                Yf[(size_t)(rbase + r) * DM + col] = acc[mt][nt][r] + bv;
        }
    }
}

// ===========================================================================
// chunk_state: Mc[j][dv] = sum_t K[t][j]*V[t][dv] (f16 plane out),
// Zc[j] = sum_t K[t][j] (f32). KTp is the f16 KT-chunk plane. LDS 18.4 KB.
// ===========================================================================
__global__ __launch_bounds__(256) void chunk_state(
    const _Float16* __restrict__ KTp, const _Float16* __restrict__ Vp,
    _Float16* __restrict__ Mc, float* __restrict__ Zc)
{
    __shared__ __align__(16) char smem[18432];
    // [0,8192) KT tile  [8192,17408) VT f16 padded  [17408,18432) scratch
    _Float16* VT = (_Float16*)(smem + 8192);
    float* scratch = (float*)(smem + 17408);

    const int blk = blockIdx.x;
    const int bh = blk / NC, c = blk % NC;
    const int b = bh / HH, h = bh % HH;
    const int tid = threadIdx.x;
    const int w = tid >> 6, lane = tid & 63;
    const int fm = lane & 15, fq = lane >> 4;
    const size_t gbase = ((size_t)(b * LL + c * CC)) * DM + h * HD;
    const _Float16* Kblk = KTp + (size_t)blk * 4096;

    stage_tile(Kblk, 64, smem, tid);

    const int lr = tid >> 2, lc0 = (tid & 3) * 16;
    // V rows (f16 plane) -> transposed VT, e-rotated scatter (2-way banks)
    {
        half8 v0 = *(const half8*)(Vp + gbase + (size_t)lr * DM + lc0);
        half8 v1 = *(const half8*)(Vp + gbase + (size_t)lr * DM + lc0 + 8);
        _Float16 va[16];
#pragma unroll
        for (int e = 0; e < 8; ++e) { va[e] = v0[e]; va[8 + e] = v1[e]; }
#pragma unroll
        for (int g = 0; g < 4; ++g)
#pragma unroll
            for (int e0 = 0; e0 < 4; ++e0) {
                const int e = g * 4 + ((e0 + tid) & 3);
                VT[(lc0 + e) * PS + lr] = va[e];
            }
    }
    // Z partials: thread (zs,zj) sums 16 t's of KT row zj (contiguous f16)
    {
        const int zj = tid & 63, zs = tid >> 6;
        half8 k0 = *(const half8*)(Kblk + zj * 64 + zs * 16);
        half8 k1 = *(const half8*)(Kblk + zj * 64 + zs * 16 + 8);
        float z = 0.f;
#pragma unroll
        for (int e = 0; e < 8; ++e) z += (float)k0[e] + (float)k1[e];
        scratch[zs * 64 + zj] = z;
    }
    __syncthreads();

    if (tid < 64) {
        Zc[(size_t)blk * 64 + tid] = scratch[tid] + scratch[64 + tid] +
                                     scratch[128 + tid] + scratch[192 + tid];
    }

    // MFMA f16: C[j][dv]; A = KT rows (swizzled tile), B = VT rows (padded)
    floatx4 acc[4];
#pragma unroll
    for (int nt = 0; nt < 4; ++nt) acc[nt] = (floatx4){0.f, 0.f, 0.f, 0.f};
    half8 aK[2];
#pragma unroll
    for (int ks = 0; ks < 2; ++ks)
        aK[ks] = frag_ldh(smem, 16 * w + fm, ks * 4 + fq);
#pragma unroll
    for (int nt = 0; nt < 4; ++nt) {
#pragma unroll
        for (int ks = 0; ks < 2; ++ks) {
            half8 bV = *(const half8*)(VT + (nt * 16 + fm) * PS + ks * 32 + fq * 8);
            acc[nt] = __builtin_amdgcn_mfma_f32_16x16x32_f16(aK[ks], bV, acc[nt], 0, 0, 0);
        }
    }
    _Float16* Mout = Mc + (size_t)blk * 4096;
#pragma unroll
    for (int nt = 0; nt < 4; ++nt) {
        const int dv = nt * 16 + fm;
#pragma unroll
        for (int r = 0; r < 4; ++r) {
            const int j = 16 * w + fq * 4 + r;
            Mout[j * 64 + dv] = (_Float16)acc[nt][r];
        }
    }
}

// ---------------------------------------------------------------------------
// exclusive prefix over chunks on the f16 Mc plane (f32 accumulator) + Z
// ---------------------------------------------------------------------------
__global__ __launch_bounds__(256) void prefix_state(
    _Float16* __restrict__ Mc, float* __restrict__ Zc)
{
    const int bh = blockIdx.x >> 4;
    const int slice = blockIdx.x & 15;
    const int off = slice * 256 + threadIdx.x;
    float run = 0.f;
    _Float16* p = Mc + (size_t)bh * NC * 4096 + off;
    for (int c = 0; c < NC; ++c) {
        const float v = (float)p[(size_t)c * 4096];
        p[(size_t)c * 4096] = (_Float16)run;
        run += v;
    }
    if (slice == 0 && threadIdx.x < 64) {
        float z = 0.f;
        float* zb = Zc + (size_t)bh * NC * 64 + threadIdx.x;
        for (int c = 0; c < NC; ++c) {
            const float v = zb[c * 64];
            zb[c * 64] = z;
            z += v;
        }
    }
}

// ===========================================================================
// chunk_attn v4 (all-f16): Q,V,KT,Mt tiles staged via global_load_lds into
// XOR-swizzled tiles; ONE barrier; A/Z/epilogue wave-local. LDS 50.3 KB
// -> 3 blk/CU. 24 MFMA/wave.
// ===========================================================================
#define ATT_Q  0
#define ATT_V  8192
#define ATT_K  16384
#define ATT_M  24576
#define ATT_A  32768   // 64 x PS f16 = 9216 B
#define ATT_Z  41984   // 64 x 65 f16 = 8320 B
__global__ __launch_bounds__(256) void chunk_attn(
    const _Float16* __restrict__ Qp, const _Float16* __restrict__ Vp,
    const _Float16* __restrict__ KTp, const _Float16* __restrict__ Mtp,
    const float* __restrict__ Zprev, unsigned short* __restrict__ Outb)
{
    __shared__ __align__(16) char smem[50304];
    _Float16* AT = (_Float16*)(smem + ATT_A);
    _Float16* Zf = (_Float16*)(smem + ATT_Z);

    const int blk = blockIdx.x;
    const int bh = blk / NC, c = blk % NC;
    const int b = bh / HH, h = bh % HH;
    const int tid = threadIdx.x;
    const int w = tid >> 6, lane = tid & 63;
    const int fm = lane & 15, fq = lane >> 4;
    const size_t gbase = ((size_t)(b * LL + c * CC)) * DM + h * HD;
    const _Float16* Kblk = KTp + (size_t)blk * 4096;

    // ---- phase 0: async staging (8 global_load_lds, zero VALU)
    stage_tile(Qp + gbase, DM, smem + ATT_Q, tid);
    stage_tile(Vp + gbase, DM, smem + ATT_V, tid);
    stage_tile(Kblk, 64, smem + ATT_K, tid);
    stage_tile(Mtp + (size_t)blk * 4096, 64, smem + ATT_M, tid);

    // Z: wave-local. Lane j of wave w computes z[i][j] for i in strip w.
    {
        const int j = lane;
        const _Float16* kr = Kblk + (size_t)j * 64;
        float run = Zprev[(size_t)blk * 64 + j];
        for (int s = 0; s < w; ++s) {   // wave-uniform bound
            half8 k0 = *(const half8*)(kr + s * 16);
            half8 k1 = *(const half8*)(kr + s * 16 + 8);
#pragma unroll
            for (int e = 0; e < 8; ++e) run += (float)k0[e] + (float)k1[e];
        }
        half8 k0 = *(const half8*)(kr + w * 16);
        half8 k1 = *(const half8*)(kr + w * 16 + 8);
        float zrow[16];
#pragma unroll
        for (int e = 0; e < 8; ++e) { run += (float)k0[e]; zrow[e] = run; }
#pragma unroll
        for (int e = 0; e < 8; ++e) { run += (float)k1[e]; zrow[8 + e] = run; }
#pragma unroll
        for (int t = 0; t < 16; ++t)
            Zf[(16 * w + t) * 65 + j] = (_Float16)zrow[t];
    }
    __syncthreads();  // the ONLY barrier (drains global_load_lds)

    // Q fragments (A-operand rows 16w+fm), reused by stage 1 and stage 2
    half8 qf[2];
#pragma unroll
    for (int ks = 0; ks < 2; ++ks)
        qf[ks] = frag_ldh(smem + ATT_Q, 16 * w + fm, ks * 4 + fq);

    // ---- stage 1: A = Q @ V^T
    floatx4 acc1[4];
#pragma unroll
    for (int nt = 0; nt < 4; ++nt) acc1[nt] = (floatx4){0.f, 0.f, 0.f, 0.f};
#pragma unroll
    for (int nt = 0; nt < 4; ++nt) {
#pragma unroll
        for (int ks = 0; ks < 2; ++ks) {
            half8 bV = frag_ldh(smem + ATT_V, nt * 16 + fm, ks * 4 + fq);
            acc1[nt] = __builtin_amdgcn_mfma_f32_16x16x32_f16(qf[ks], bV, acc1[nt], 0, 0, 0);
        }
    }

    // write tril(A) f16 (wave-local rows, padded stride, r-rotated)
#pragma unroll
    for (int nt = 0; nt < 4; ++nt) {
        const int t = nt * 16 + fm;
#pragma unroll
        for (int r0 = 0; r0 < 4; ++r0) {
            const int r = (r0 + fm) & 3;
            const int i = 16 * w + fq * 4 + r;
            AT[i * PS + t] = (_Float16)((t <= i) ? acc1[nt][r] : 0.f);
        }
    }

    // ---- stage 2: num = Q@Mt + A@KT  (no barrier: A rows are wave-local)
    floatx4 acc2[4];
#pragma unroll
    for (int nt = 0; nt < 4; ++nt) acc2[nt] = (floatx4){0.f, 0.f, 0.f, 0.f};
    {
        half8 aA[2];
#pragma unroll
        for (int ks = 0; ks < 2; ++ks)
            aA[ks] = *(const half8*)(AT + (16 * w + fm) * PS + ks * 32 + fq * 8);
#pragma unroll
        for (int nt = 0; nt < 4; ++nt) {
#pragma unroll
            for (int ks = 0; ks < 2; ++ks) {
                half8 bM = frag_ldh(smem + ATT_M, nt * 16 + fm, ks * 4 + fq);
                acc2[nt] = __builtin_amdgcn_mfma_f32_16x16x32_f16(qf[ks], bM, acc2[nt], 0, 0, 0);
            }
#pragma unroll
            for (int ks = 0; ks < 2; ++ks) {
                half8 bK = frag_ldh(smem + ATT_K, nt * 16 + fm, ks * 4 + fq);
                acc2[nt] = __builtin_amdgcn_mfma_f32_16x16x32_f16(aA[ks], bK, acc2[nt], 0, 0, 0);
            }
        }
    }

    // ---- epilogue (wave-local Zf strip + swizzled Q reads), out bf16
#pragma unroll
    for (int nt = 0; nt < 4; ++nt) {
        const int j = nt * 16 + fm;
#pragma unroll
        for (int r = 0; r < 4; ++r) {
            const int i = 16 * w + fq * 4 + r;
            const int qoff = i * 128 + (((j >> 3) ^ (i & 7)) << 4) + (j & 7) * 2;
            const float q = (float)(*(const _Float16*)(smem + ATT_Q + qoff));
            const float z = (float)Zf[i * 65 + j];
            const float denom = fmaf(q, z, EPSC);
            Outb[gbase + (size_t)i * DM + j] = f2bf(acc2[nt][r] * __builtin_amdgcn_rcpf(denom));
        }
    }
}

// ---------------------------------------------------------------------------
// Launch.  Workspace map (byte offsets, NO overlaps):
//   [ 48, 56) Wt x4   8 MB
//   [ 56, 72) Qh   f16 8.4M = 16 MB            [ 72, 88) Vh     16 MB
//   [ 88,104) KTp  f16 16 MB                   [104,120) Mc f16 16 MB
//   [120,121) Zc   f32 0.5 MB                  [128,144) attnb  16 MB
//   (f32->bf16 convert of q,k,v is fused into gemm_qkv; no qb/kb/vb)
// ---------------------------------------------------------------------------
extern "C" void kernel_launch(void* const* d_in, const int* in_sizes, int n_in,
                              void* d_out, int out_size, void* d_ws, size_t ws_size,
                              hipStream_t stream)
{
    (void)in_sizes; (void)n_in; (void)out_size; (void)ws_size;

    const float* queries = (const float*)d_in[0];
    const float* keys    = (const float*)d_in[1];
    const float* values  = (const float*)d_in[2];
    const float* Wq = (const float*)d_in[3];
    const float* bq = (const float*)d_in[4];
    const float* Wk = (const float*)d_in[5];
    const float* bk = (const float*)d_in[6];
    const float* Wv = (const float*)d_in[7];
    const float* bv = (const float*)d_in[8];
    const float* Wo = (const float*)d_in[9];
    const float* bo = (const float*)d_in[10];

    char* ws = (char*)d_ws;
    const size_t MB = 1u << 20;
    unsigned short* Wqt = (unsigned short*)(ws + 48 * MB);
    unsigned short* Wkt = (unsigned short*)(ws + 50 * MB);
    unsigned short* Wvt = (unsigned short*)(ws + 52 * MB);
    unsigned short* Wot = (unsigned short*)(ws + 54 * MB);
    _Float16* Qh  = (_Float16*)(ws + 56 * MB);
    _Float16* Vh  = (_Float16*)(ws + 72 * MB);
    _Float16* KTp = (_Float16*)(ws + 88 * MB);
    _Float16* Mc  = (_Float16*)(ws + 104 * MB);
    float* Zc     = (float*)(ws + 120 * MB);
    unsigned short* attnb = (unsigned short*)(ws + 128 * MB);

    const dim3 gblk(256);

    transpose4<<<dim3(16, 16, 4), gblk, 0, stream>>>(Wq, Wk, Wv, Wo, Wqt, Wkt, Wvt, Wot);

    gemm_qkv<<<dim3(512, 3), gblk, 0, stream>>>(queries, keys, values,
                                                Wqt, Wkt, Wvt, bq, bk, bv,
                                                Qh, KTp, Vh);

    chunk_state<<<dim3(BB * HH * NC), gblk, 0, stream>>>(KTp, Vh, Mc, Zc);
    prefix_state<<<dim3(BB * HH * 16), gblk, 0, stream>>>(Mc, Zc);
    chunk_attn<<<dim3(BB * HH * NC), gblk, 0, stream>>>(Qh, Vh, KTp, Mc, Zc, attnb);

    gemm_out<<<dim3(512), gblk, 0, stream>>>(attnb, Wot, bo, (float*)d_out);
}

// Round 2
// 321.312 us; speedup vs baseline: 1.0607x; 1.0607x over previous
//
#include <hip/hip_runtime.h>
#include <math.h>

// Problem constants
#define DM 1024      // d_model
#define LL 2048      // sequence length
#define BB 4         // batch
#define HH 16        // heads
#define HD 64        // head dim
#define CC 64        // chunk size
#define NC (LL / CC) // 32 chunks
#define EPSC 1e-6f
#define PS 72        // padded LDS stride (elements) for VALU-written 64-wide tiles

typedef __attribute__((ext_vector_type(8))) short short8;      // 8 bf16
typedef __attribute__((ext_vector_type(8))) _Float16 half8;    // 8 f16
typedef __attribute__((ext_vector_type(4))) float floatx4;     // MFMA acc

__device__ __forceinline__ float featf(float x) { return x > 0.f ? x + 1.f : __expf(x); }

// round-to-nearest-even f32 -> bf16 bits
__device__ __forceinline__ unsigned short f2bf(float f) {
    unsigned int u = __builtin_bit_cast(unsigned int, f);
    u = (u + 0x7FFFu + ((u >> 16) & 1u)) >> 16;
    return (unsigned short)u;
}

// 8x f32 -> 8x bf16 via hardware pk converts (RNE, matches f2bf).
// Returns uint4 so the LDS store is a single ds_write_b128 (conflict-free
// linear b128); round-0's short8-union path appears to have been split into
// b32 stores (16B-stride lanes = 8-way bank conflict, 6.3M counted).
__device__ __forceinline__ uint4 cvt8(float4 a, float4 b) {
    uint4 r;
    asm("v_cvt_pk_bf16_f32 %0, %1, %2" : "=v"(r.x) : "v"(a.x), "v"(a.y));
    asm("v_cvt_pk_bf16_f32 %0, %1, %2" : "=v"(r.y) : "v"(a.z), "v"(a.w));
    asm("v_cvt_pk_bf16_f32 %0, %1, %2" : "=v"(r.z) : "v"(b.x), "v"(b.y));
    asm("v_cvt_pk_bf16_f32 %0, %1, %2" : "=v"(r.w) : "v"(b.z), "v"(b.w));
    return r;
}

__device__ __forceinline__ void gload_lds16(const void* g, void* l) {
    __builtin_amdgcn_global_load_lds(
        (const __attribute__((address_space(1))) void*)g,
        (__attribute__((address_space(3))) void*)l,
        16, 0, 0);
}

// Stage a 64x64 2-byte-element tile (8 KB) global -> LDS, XOR-8 chunk swizzle
// baked into the SOURCE address. LDS: row*128B + slot*16B, slot = g ^ (row&7).
__device__ __forceinline__ void stage_tile(const void* gp_, int rowstride,
                                           char* lds_base, int tid) {
    const unsigned short* gp = (const unsigned short*)gp_;
#pragma unroll
    for (int m = 0; m < 2; ++m) {
        const int row = m * 32 + (tid >> 3);
        const int g = (tid & 7) ^ (row & 7);
        gload_lds16(gp + (size_t)row * rowstride + g * 8,
                    lds_base + m * 4096 + tid * 16);
    }
}
__device__ __forceinline__ half8 frag_ldh(const char* base, int row, int kc) {
    return *(const half8*)(base + row * 128 + (((kc) ^ (row & 7)) << 4));
}

// ---------------------------------------------------------------------------
// fused weight transpose+convert: W [K][N] f32 -> Wt [N][K] bf16, 4 weights
// ---------------------------------------------------------------------------
__global__ __launch_bounds__(256) void transpose4(
    const float* __restrict__ W0, const float* __restrict__ W1,
    const float* __restrict__ W2, const float* __restrict__ W3,
    unsigned short* __restrict__ T0, unsigned short* __restrict__ T1,
    unsigned short* __restrict__ T2, unsigned short* __restrict__ T3)
{
    __shared__ float tile[64][65];
    const int sel = blockIdx.z;
    const float* W = (sel == 0) ? W0 : (sel == 1) ? W1 : (sel == 2) ? W2 : W3;
    unsigned short* Wt = (sel == 0) ? T0 : (sel == 1) ? T1 : (sel == 2) ? T2 : T3;
    const int r0 = blockIdx.y * 64, c0 = blockIdx.x * 64;
    const int tid = threadIdx.x;
#pragma unroll
    for (int e = 0; e < 16; ++e) {
        const int idx = e * 256 + tid;
        const int r = idx >> 6, c = idx & 63;
        tile[r][c] = W[(size_t)(r0 + r) * DM + c0 + c];
    }
    __syncthreads();
#pragma unroll
    for (int e = 0; e < 16; ++e) {
        const int idx = e * 256 + tid;
        const int co = idx >> 6, ro = idx & 63;
        Wt[(size_t)(c0 + co) * DM + r0 + ro] = f2bf(tile[ro][co]);
    }
}

// ===========================================================================
// gemm_qkv: fused f32->bf16 convert + MFMA GEMM for the three projections.
// A-side: f32 loads prefetched one k-step ahead, cvt_pk in regs, ds_write_b128
// into the XOR-swizzled tile. B-side: bf16 Wt via global_load_lds.
// Barrier structure: barrier1 = full __syncthreads (must drain B gload_lds +
// make A ds_writes visible). barrier2 = RAW s_barrier (no vmcnt drain) — it
// only guards read-before-overwrite, and each wave's ds_reads are lgkm-waited
// before its MFMAs, so no drain is needed. This keeps the f32 prefetch in
// flight across barrier2 (round-0's __syncthreads here drained it every
// k-step = the 156us stall).
// ===========================================================================
__global__ __launch_bounds__(256) void gemm_qkv(
    const float* __restrict__ Xq, const float* __restrict__ Xk,
    const float* __restrict__ Xv,
    const unsigned short* __restrict__ Wqt, const unsigned short* __restrict__ Wkt,
    const unsigned short* __restrict__ Wvt,
    const float* __restrict__ bq, const float* __restrict__ bk,
    const float* __restrict__ bv,
    _Float16* __restrict__ Qh, _Float16* __restrict__ KTp,
    _Float16* __restrict__ Vh)
{
    __shared__ __align__(16) unsigned short As[128 * 32];
    __shared__ __align__(16) unsigned short Bs[128 * 32];

    const int sel = blockIdx.y;
    const float* Xf = (sel == 0) ? Xq : (sel == 1) ? Xk : Xv;
    const unsigned short* Wt = (sel == 0) ? Wqt : (sel == 1) ? Wkt : Wvt;
    const float* bias = (sel == 0) ? bq : (sel == 1) ? bk : bv;

    const int tid = threadIdx.x;
    const int lane = tid & 63;
    const int w = tid >> 6;
    const int wr = w >> 1, wc = w & 1;
    const int fm = lane & 15;
    const int fq = lane >> 4;
    // bijective XCD-chunk swizzle: XCD x gets 8 complete m-strips (all n)
    const int t = (blockIdx.x & 7) * 64 + (blockIdx.x >> 3);
    const int n0 = (t & 7) * 128, m0 = (t >> 3) * 128;

    floatx4 acc[4][4];
#pragma unroll
    for (int i = 0; i < 4; ++i)
#pragma unroll
        for (int j = 0; j < 4; ++j) acc[i][j] = (floatx4){0.f, 0.f, 0.f, 0.f};

    const int row0 = tid >> 2;
    const int row1 = row0 + 64;
    const int slot0 = (tid & 3) ^ (row0 & 3);
    const int slot1 = (tid & 3) ^ (row1 & 3);
    const float* Xa = Xf + (size_t)(m0 + row0) * DM + slot0 * 8;
    const float* Xb = Xf + (size_t)(m0 + row1) * DM + slot1 * 8;
    const unsigned short* Wa = Wt + (size_t)(n0 + row0) * DM + slot0 * 8;
    const unsigned short* Wb = Wt + (size_t)(n0 + row1) * DM + slot1 * 8;

    const int fswz = ((fq ^ (fm & 3)) << 3);

    // prologue: k0 = 0 A-tile loads
    float4 ra0 = *(const float4*)(Xa);
    float4 ra1 = *(const float4*)(Xa + 4);
    float4 rb0 = *(const float4*)(Xb);
    float4 rb1 = *(const float4*)(Xb + 4);

    for (int k0 = 0; k0 < DM; k0 += 32) {
        gload_lds16(Wa + k0, Bs + (size_t)tid * 8);
        gload_lds16(Wb + k0, Bs + (size_t)(256 + tid) * 8);
        *(uint4*)(As + (size_t)tid * 8) = cvt8(ra0, ra1);
        *(uint4*)(As + (size_t)(256 + tid) * 8) = cvt8(rb0, rb1);
        __syncthreads();   // barrier1: drain B gload_lds + A ds_writes visible

        // issue next k-step's f32 loads; they stay in flight through the MFMA
        // block AND the raw barrier2 below, completing before next cvt8.
        const int kn = (k0 + 32 < DM) ? (k0 + 32) : 0;
        ra0 = *(const float4*)(Xa + kn);
        ra1 = *(const float4*)(Xa + kn + 4);
        rb0 = *(const float4*)(Xb + kn);
        rb1 = *(const float4*)(Xb + kn + 4);

        short8 af[4], bf[4];
#pragma unroll
        for (int mt = 0; mt < 4; ++mt)
            af[mt] = *(const short8*)(As + (wr * 64 + mt * 16 + fm) * 32 + fswz);
#pragma unroll
        for (int nt = 0; nt < 4; ++nt)
            bf[nt] = *(const short8*)(Bs + (wc * 64 + nt * 16 + fm) * 32 + fswz);
#pragma unroll
        for (int mt = 0; mt < 4; ++mt)
#pragma unroll
            for (int nt = 0; nt < 4; ++nt)
                acc[mt][nt] = __builtin_amdgcn_mfma_f32_16x16x32_bf16(
                    af[mt], bf[nt], acc[mt][nt], 0, 0, 0);

        // barrier2: RAW s_barrier, no vmcnt drain (prefetch survives).
        __builtin_amdgcn_sched_barrier(0);
        __builtin_amdgcn_s_barrier();
        __builtin_amdgcn_sched_barrier(0);
    }

    if (sel != 1) {
        // row-major f16 plane out (Q with act, V without)
        const int act = (sel == 0);
        _Float16* Yh = (sel == 0) ? Qh : Vh;
#pragma unroll
        for (int nt = 0; nt < 4; ++nt) {
            const int col = n0 + wc * 64 + nt * 16 + fm;
            const float bvv = bias[col];
#pragma unroll
            for (int mt = 0; mt < 4; ++mt) {
                const int rbase = m0 + wr * 64 + mt * 16 + fq * 4;
#pragma unroll
                for (int r = 0; r < 4; ++r) {
                    float v = acc[mt][nt][r] + bvv;
                    if (act) v = featf(v);
                    Yh[(size_t)(rbase + r) * DM + col] = (_Float16)v;
                }
            }
        }
    } else {
        // KT-chunk layout [blk][j][t], blk = (b*16+h)*32 + chunk; act always
        const int b = m0 >> 11;
        const int cch = ((m0 & 2047) >> 6) + wr;
        const int h = (n0 >> 6) + wc;
        _Float16* hb = KTp + ((size_t)((b * 16 + h) * 32 + cch)) * 4096;
#pragma unroll
        for (int nt = 0; nt < 4; ++nt) {
            const int j = nt * 16 + fm;
            const float bvv = bias[n0 + wc * 64 + nt * 16 + fm];
#pragma unroll
            for (int mt = 0; mt < 4; ++mt) {
                float o[4];
#pragma unroll
                for (int r = 0; r < 4; ++r)
                    o[r] = featf(acc[mt][nt][r] + bvv);
                union { _Float16 h[4]; uint2 v; } pk;
#pragma unroll
                for (int r = 0; r < 4; ++r) pk.h[r] = (_Float16)o[r];
                *(uint2*)(hb + j * 64 + mt * 16 + fq * 4) = pk.v;
            }
        }
    }
}

// ---------------------------------------------------------------------------
// gemm_out: bf16 MFMA GEMM, f32 rows out (final output projection)
// ---------------------------------------------------------------------------
__global__ __launch_bounds__(256) void gemm_out(
    const unsigned short* __restrict__ X,
    const unsigned short* __restrict__ Wt,
    const float* __restrict__ bias,
    float* __restrict__ Yf)
{
    __shared__ __align__(16) unsigned short As[128 * 32];
    __shared__ __align__(16) unsigned short Bs[128 * 32];

    const int tid = threadIdx.x;
    const int lane = tid & 63;
    const int w = tid >> 6;
    const int wr = w >> 1, wc = w & 1;
    const int fm = lane & 15;
    const int fq = lane >> 4;
    const int t = (blockIdx.x & 7) * 64 + (blockIdx.x >> 3);
    const int n0 = (t & 7) * 128, m0 = (t >> 3) * 128;

    floatx4 acc[4][4];
#pragma unroll
    for (int i = 0; i < 4; ++i)
#pragma unroll
        for (int j = 0; j < 4; ++j) acc[i][j] = (floatx4){0.f, 0.f, 0.f, 0.f};

    const int row0 = tid >> 2;
    const int row1 = row0 + 64;
    const int slot0 = (tid & 3) ^ (row0 & 3);
    const int slot1 = (tid & 3) ^ (row1 & 3);
    const unsigned short* Xa = X + (size_t)(m0 + row0) * DM + slot0 * 8;
    const unsigned short* Xb = X + (size_t)(m0 + row1) * DM + slot1 * 8;
    const unsigned short* Wa = Wt + (size_t)(n0 + row0) * DM + slot0 * 8;
    const unsigned short* Wb = Wt + (size_t)(n0 + row1) * DM + slot1 * 8;

    const int fswz = ((fq ^ (fm & 3)) << 3);

    for (int k0 = 0; k0 < DM; k0 += 32) {
        gload_lds16(Xa + k0, As + (size_t)tid * 8);
        gload_lds16(Xb + k0, As + (size_t)(256 + tid) * 8);
        gload_lds16(Wa + k0, Bs + (size_t)tid * 8);
        gload_lds16(Wb + k0, Bs + (size_t)(256 + tid) * 8);
        __syncthreads();

        short8 af[4], bf[4];
#pragma unroll
        for (int mt = 0; mt < 4; ++mt)
            af[mt] = *(const short8*)(As + (wr * 64 + mt * 16 + fm) * 32 + fswz);
#pragma unroll
        for (int nt = 0; nt < 4; ++nt)
            bf[nt] = *(const short8*)(Bs + (wc * 64 + nt * 16 + fm) * 32 + fswz);
#pragma unroll
        for (int mt = 0; mt < 4; ++mt)
#pragma unroll
            for (int nt = 0; nt < 4; ++nt)
                acc[mt][nt] = __builtin_amdgcn_mfma_f32_16x16x32_bf16(
                    af[mt], bf[nt], acc[mt][nt], 0, 0, 0);
        __syncthreads();
    }

#pragma unroll
    for (int nt = 0; nt < 4; ++nt) {
        const int col = n0 + wc * 64 + nt * 16 + fm;
        const float bv = bias[col];
#pragma unroll
        for (int mt = 0; mt < 4; ++mt) {
            const int rbase = m0 + wr * 64 + mt * 16 + fq * 4;
#pragma unroll
            for (int r = 0; r < 4; ++r)
                Yf[(size_t)(rbase + r) * DM + col] = acc[mt][nt][r] + bv;
        }
    }
}

// ===========================================================================
// chunk_state: Mc[j][dv] = sum_t K[t][j]*V[t][dv] (f16 plane out),
// Zc[j] = sum_t K[t][j] (f32). KTp is the f16 KT-chunk plane. LDS 18.4 KB.
// ===========================================================================
__global__ __launch_bounds__(256) void chunk_state(
    const _Float16* __restrict__ KTp, const _Float16* __restrict__ Vp,
    _Float16* __restrict__ Mc, float* __restrict__ Zc)
{
    __shared__ __align__(16) char smem[18432];
    // [0,8192) KT tile  [8192,17408) VT f16 padded  [17408,18432) scratch
    _Float16* VT = (_Float16*)(smem + 8192);
    float* scratch = (float*)(smem + 17408);

    const int blk = blockIdx.x;
    const int bh = blk / NC, c = blk % NC;
    const int b = bh / HH, h = bh % HH;
    const int tid = threadIdx.x;
    const int w = tid >> 6, lane = tid & 63;
    const int fm = lane & 15, fq = lane >> 4;
    const size_t gbase = ((size_t)(b * LL + c * CC)) * DM + h * HD;
    const _Float16* Kblk = KTp + (size_t)blk * 4096;

    stage_tile(Kblk, 64, smem, tid);

    const int lr = tid >> 2, lc0 = (tid & 3) * 16;
    // V rows (f16 plane) -> transposed VT, e-rotated scatter (2-way banks)
    {
        half8 v0 = *(const half8*)(Vp + gbase + (size_t)lr * DM + lc0);
        half8 v1 = *(const half8*)(Vp + gbase + (size_t)lr * DM + lc0 + 8);
        _Float16 va[16];
#pragma unroll
        for (int e = 0; e < 8; ++e) { va[e] = v0[e]; va[8 + e] = v1[e]; }
#pragma unroll
        for (int g = 0; g < 4; ++g)
#pragma unroll
            for (int e0 = 0; e0 < 4; ++e0) {
                const int e = g * 4 + ((e0 + tid) & 3);
                VT[(lc0 + e) * PS + lr] = va[e];
            }
    }
    // Z partials: thread (zs,zj) sums 16 t's of KT row zj (contiguous f16)
    {
        const int zj = tid & 63, zs = tid >> 6;
        half8 k0 = *(const half8*)(Kblk + zj * 64 + zs * 16);
        half8 k1 = *(const half8*)(Kblk + zj * 64 + zs * 16 + 8);
        float z = 0.f;
#pragma unroll
        for (int e = 0; e < 8; ++e) z += (float)k0[e] + (float)k1[e];
        scratch[zs * 64 + zj] = z;
    }
    __syncthreads();

    if (tid < 64) {
        Zc[(size_t)blk * 64 + tid] = scratch[tid] + scratch[64 + tid] +
                                     scratch[128 + tid] + scratch[192 + tid];
    }

    // MFMA f16: C[j][dv]; A = KT rows (swizzled tile), B = VT rows (padded)
    floatx4 acc[4];
#pragma unroll
    for (int nt = 0; nt < 4; ++nt) acc[nt] = (floatx4){0.f, 0.f, 0.f, 0.f};
    half8 aK[2];
#pragma unroll
    for (int ks = 0; ks < 2; ++ks)
        aK[ks] = frag_ldh(smem, 16 * w + fm, ks * 4 + fq);
#pragma unroll
    for (int nt = 0; nt < 4; ++nt) {
#pragma unroll
        for (int ks = 0; ks < 2; ++ks) {
            half8 bV = *(const half8*)(VT + (nt * 16 + fm) * PS + ks * 32 + fq * 8);
            acc[nt] = __builtin_amdgcn_mfma_f32_16x16x32_f16(aK[ks], bV, acc[nt], 0, 0, 0);
        }
    }
    _Float16* Mout = Mc + (size_t)blk * 4096;
#pragma unroll
    for (int nt = 0; nt < 4; ++nt) {
        const int dv = nt * 16 + fm;
#pragma unroll
        for (int r = 0; r < 4; ++r) {
            const int j = 16 * w + fq * 4 + r;
            Mout[j * 64 + dv] = (_Float16)acc[nt][r];
        }
    }
}

// ---------------------------------------------------------------------------
// exclusive prefix over chunks on the f16 Mc plane (f32 accumulator) + Z
// ---------------------------------------------------------------------------
__global__ __launch_bounds__(256) void prefix_state(
    _Float16* __restrict__ Mc, float* __restrict__ Zc)
{
    const int bh = blockIdx.x >> 4;
    const int slice = blockIdx.x & 15;
    const int off = slice * 256 + threadIdx.x;
    float run = 0.f;
    _Float16* p = Mc + (size_t)bh * NC * 4096 + off;
    for (int c = 0; c < NC; ++c) {
        const float v = (float)p[(size_t)c * 4096];
        p[(size_t)c * 4096] = (_Float16)run;
        run += v;
    }
    if (slice == 0 && threadIdx.x < 64) {
        float z = 0.f;
        float* zb = Zc + (size_t)bh * NC * 64 + threadIdx.x;
        for (int c = 0; c < NC; ++c) {
            const float v = zb[c * 64];
            zb[c * 64] = z;
            z += v;
        }
    }
}

// ===========================================================================
// chunk_attn v4 (all-f16): Q,V,KT,Mt tiles staged via global_load_lds into
// XOR-swizzled tiles; ONE barrier; A/Z/epilogue wave-local. LDS 50.3 KB
// -> 3 blk/CU. 24 MFMA/wave.
// ===========================================================================
#define ATT_Q  0
#define ATT_V  8192
#define ATT_K  16384
#define ATT_M  24576
#define ATT_A  32768   // 64 x PS f16 = 9216 B
#define ATT_Z  41984   // 64 x 65 f16 = 8320 B
__global__ __launch_bounds__(256) void chunk_attn(
    const _Float16* __restrict__ Qp, const _Float16* __restrict__ Vp,
    const _Float16* __restrict__ KTp, const _Float16* __restrict__ Mtp,
    const float* __restrict__ Zprev, unsigned short* __restrict__ Outb)
{
    __shared__ __align__(16) char smem[50304];
    _Float16* AT = (_Float16*)(smem + ATT_A);
    _Float16* Zf = (_Float16*)(smem + ATT_Z);

    const int blk = blockIdx.x;
    const int bh = blk / NC, c = blk % NC;
    const int b = bh / HH, h = bh % HH;
    const int tid = threadIdx.x;
    const int w = tid >> 6, lane = tid & 63;
    const int fm = lane & 15, fq = lane >> 4;
    const size_t gbase = ((size_t)(b * LL + c * CC)) * DM + h * HD;
    const _Float16* Kblk = KTp + (size_t)blk * 4096;

    // ---- phase 0: async staging (8 global_load_lds, zero VALU)
    stage_tile(Qp + gbase, DM, smem + ATT_Q, tid);
    stage_tile(Vp + gbase, DM, smem + ATT_V, tid);
    stage_tile(Kblk, 64, smem + ATT_K, tid);
    stage_tile(Mtp + (size_t)blk * 4096, 64, smem + ATT_M, tid);

    // Z: wave-local. Lane j of wave w computes z[i][j] for i in strip w.
    {
        const int j = lane;
        const _Float16* kr = Kblk + (size_t)j * 64;
        float run = Zprev[(size_t)blk * 64 + j];
        for (int s = 0; s < w; ++s) {   // wave-uniform bound
            half8 k0 = *(const half8*)(kr + s * 16);
            half8 k1 = *(const half8*)(kr + s * 16 + 8);
#pragma unroll
            for (int e = 0; e < 8; ++e) run += (float)k0[e] + (float)k1[e];
        }
        half8 k0 = *(const half8*)(kr + w * 16);
        half8 k1 = *(const half8*)(kr + w * 16 + 8);
        float zrow[16];
#pragma unroll
        for (int e = 0; e < 8; ++e) { run += (float)k0[e]; zrow[e] = run; }
#pragma unroll
        for (int e = 0; e < 8; ++e) { run += (float)k1[e]; zrow[8 + e] = run; }
#pragma unroll
        for (int t = 0; t < 16; ++t)
            Zf[(16 * w + t) * 65 + j] = (_Float16)zrow[t];
    }
    __syncthreads();  // the ONLY barrier (drains global_load_lds)

    // Q fragments (A-operand rows 16w+fm), reused by stage 1 and stage 2
    half8 qf[2];
#pragma unroll
    for (int ks = 0; ks < 2; ++ks)
        qf[ks] = frag_ldh(smem + ATT_Q, 16 * w + fm, ks * 4 + fq);

    // ---- stage 1: A = Q @ V^T
    floatx4 acc1[4];
#pragma unroll
    for (int nt = 0; nt < 4; ++nt) acc1[nt] = (floatx4){0.f, 0.f, 0.f, 0.f};
#pragma unroll
    for (int nt = 0; nt < 4; ++nt) {
#pragma unroll
        for (int ks = 0; ks < 2; ++ks) {
            half8 bV = frag_ldh(smem + ATT_V, nt * 16 + fm, ks * 4 + fq);
            acc1[nt] = __builtin_amdgcn_mfma_f32_16x16x32_f16(qf[ks], bV, acc1[nt], 0, 0, 0);
        }
    }

    // write tril(A) f16 (wave-local rows, padded stride, r-rotated)
#pragma unroll
    for (int nt = 0; nt < 4; ++nt) {
        const int t = nt * 16 + fm;
#pragma unroll
        for (int r0 = 0; r0 < 4; ++r0) {
            const int r = (r0 + fm) & 3;
            const int i = 16 * w + fq * 4 + r;
            AT[i * PS + t] = (_Float16)((t <= i) ? acc1[nt][r] : 0.f);
        }
    }

    // ---- stage 2: num = Q@Mt + A@KT  (no barrier: A rows are wave-local)
    floatx4 acc2[4];
#pragma unroll
    for (int nt = 0; nt < 4; ++nt) acc2[nt] = (floatx4){0.f, 0.f, 0.f, 0.f};
    {
        half8 aA[2];
#pragma unroll
        for (int ks = 0; ks < 2; ++ks)
            aA[ks] = *(const half8*)(AT + (16 * w + fm) * PS + ks * 32 + fq * 8);
#pragma unroll
        for (int nt = 0; nt < 4; ++nt) {
#pragma unroll
            for (int ks = 0; ks < 2; ++ks) {
                half8 bM = frag_ldh(smem + ATT_M, nt * 16 + fm, ks * 4 + fq);
                acc2[nt] = __builtin_amdgcn_mfma_f32_16x16x32_f16(qf[ks], bM, acc2[nt], 0, 0, 0);
            }
#pragma unroll
            for (int ks = 0; ks < 2; ++ks) {
                half8 bK = frag_ldh(smem + ATT_K, nt * 16 + fm, ks * 4 + fq);
                acc2[nt] = __builtin_amdgcn_mfma_f32_16x16x32_f16(aA[ks], bK, acc2[nt], 0, 0, 0);
            }
        }
    }

    // ---- epilogue (wave-local Zf strip + swizzled Q reads), out bf16
#pragma unroll
    for (int nt = 0; nt < 4; ++nt) {
        const int j = nt * 16 + fm;
#pragma unroll
        for (int r = 0; r < 4; ++r) {
            const int i = 16 * w + fq * 4 + r;
            const int qoff = i * 128 + (((j >> 3) ^ (i & 7)) << 4) + (j & 7) * 2;
            const float q = (float)(*(const _Float16*)(smem + ATT_Q + qoff));
            const float z = (float)Zf[i * 65 + j];
            const float denom = fmaf(q, z, EPSC);
            Outb[gbase + (size_t)i * DM + j] = f2bf(acc2[nt][r] * __builtin_amdgcn_rcpf(denom));
        }
    }
}

// ---------------------------------------------------------------------------
// Launch.  Workspace map (byte offsets, NO overlaps):
//   [ 48, 56) Wt x4   8 MB
//   [ 56, 72) Qh   f16 8.4M = 16 MB            [ 72, 88) Vh     16 MB
//   [ 88,104) KTp  f16 16 MB                   [104,120) Mc f16 16 MB
//   [120,121) Zc   f32 0.5 MB                  [128,144) attnb  16 MB
//   (f32->bf16 convert of q,k,v is fused into gemm_qkv; no qb/kb/vb)
// ---------------------------------------------------------------------------
extern "C" void kernel_launch(void* const* d_in, const int* in_sizes, int n_in,
                              void* d_out, int out_size, void* d_ws, size_t ws_size,
                              hipStream_t stream)
{
    (void)in_sizes; (void)n_in; (void)out_size; (void)ws_size;

    const float* queries = (const float*)d_in[0];
    const float* keys    = (const float*)d_in[1];
    const float* values  = (const float*)d_in[2];
    const float* Wq = (const float*)d_in[3];
    const float* bq = (const float*)d_in[4];
    const float* Wk = (const float*)d_in[5];
    const float* bk = (const float*)d_in[6];
    const float* Wv = (const float*)d_in[7];
    const float* bv = (const float*)d_in[8];
    const float* Wo = (const float*)d_in[9];
    const float* bo = (const float*)d_in[10];

    char* ws = (char*)d_ws;
    const size_t MB = 1u << 20;
    unsigned short* Wqt = (unsigned short*)(ws + 48 * MB);
    unsigned short* Wkt = (unsigned short*)(ws + 50 * MB);
    unsigned short* Wvt = (unsigned short*)(ws + 52 * MB);
    unsigned short* Wot = (unsigned short*)(ws + 54 * MB);
    _Float16* Qh  = (_Float16*)(ws + 56 * MB);
    _Float16* Vh  = (_Float16*)(ws + 72 * MB);
    _Float16* KTp = (_Float16*)(ws + 88 * MB);
    _Float16* Mc  = (_Float16*)(ws + 104 * MB);
    float* Zc     = (float*)(ws + 120 * MB);
    unsigned short* attnb = (unsigned short*)(ws + 128 * MB);

    const dim3 gblk(256);

    transpose4<<<dim3(16, 16, 4), gblk, 0, stream>>>(Wq, Wk, Wv, Wo, Wqt, Wkt, Wvt, Wot);

    gemm_qkv<<<dim3(512, 3), gblk, 0, stream>>>(queries, keys, values,
                                                Wqt, Wkt, Wvt, bq, bk, bv,
                                                Qh, KTp, Vh);

    chunk_state<<<dim3(BB * HH * NC), gblk, 0, stream>>>(KTp, Vh, Mc, Zc);
    prefix_state<<<dim3(BB * HH * 16), gblk, 0, stream>>>(Mc, Zc);
    chunk_attn<<<dim3(BB * HH * NC), gblk, 0, stream>>>(Qh, Vh, KTp, Mc, Zc, attnb);

    gemm_out<<<dim3(512), gblk, 0, stream>>>(attnb, Wot, bo, (float*)d_out);
}